// Round 6
// baseline (671.278 us; speedup 1.0000x reference)
//
#include <hip/hip_runtime.h>
#include <stdint.h>
#include <float.h>
#include <limits.h>

// ---------------------------------------------------------------------------
// Sampler: logits = (h @ E^T + bias) / T; softmax; top-p/top-k mask;
// jax.random.categorical(key(42)) == argmax(logp + gumbel) over kept set.
// GEMM via bf16 MFMA, 3-term split (loA*hiB + hiA*loB + hiA*hiB), k-ascending.
// Round 6: DRAM-burst restage. Each wave-instruction loads 1 KB contiguous
// from ONE emb row (64 lanes x 16 B) into a per-wave-private LDS window
// (fp32, XOR-swizzled). No barriers anywhere: each wave writes/reads only its
// own 16 LDS rows. Window = 256 k-floats (8 MFMA k-tiles); loads for window
// w+1 issue before compute of window w. A stays frag-ordered in L2.
// ---------------------------------------------------------------------------

typedef __bf16 bf16x8 __attribute__((ext_vector_type(8)));
typedef float  f32x4  __attribute__((ext_vector_type(4)));

// pack 8 floats -> hi bf16 (RNE) + lo bf16 (RNE of residual)
__device__ __forceinline__ void split8v(const float* f, bf16x8& hi, bf16x8& lo) {
#pragma unroll
    for (int e = 0; e < 8; ++e) {
        const __bf16 h = (__bf16)f[e];
        hi[e] = h;
        lo[e] = (__bf16)(f[e] - (float)h);
    }
}
__device__ __forceinline__ void split8(const float* f, uint4& hi, uint4& lo) {
    bf16x8 vh, vl;
    split8v(f, vh, vl);
    hi = __builtin_bit_cast(uint4, vh);
    lo = __builtin_bit_cast(uint4, vl);
}

// ---------------------------------------------------------------------------
// prep: h[b, pos, :] -> A_hi/A_lo in MFMA fragment order (verified layout):
// idx = ((r16*128 + kc)*64 + lh*16 + ll)*8 + j ; row = r16*16+ll,
// k = kc*32 + lh*8 + j.
// ---------------------------------------------------------------------------
__global__ __launch_bounds__(256) void prep_h(
    const float* __restrict__ hs, const int* __restrict__ pos_p,
    unsigned short* __restrict__ Ahi, unsigned short* __restrict__ Alo,
    int H, int L)
{
    const int pos = pos_p[0];
    const int tid = blockIdx.x * 256 + threadIdx.x;   // B*H/16 threads
    const int b     = tid >> 8;                       // 0..63
    const int kbase = (tid & 255) * 16;               // 0..4080
    const float* src = hs + ((size_t)b * L + pos) * H + kbase;
    float f[16];
    *(float4*)&f[0]  = *(const float4*)(src);
    *(float4*)&f[4]  = *(const float4*)(src + 4);
    *(float4*)&f[8]  = *(const float4*)(src + 8);
    *(float4*)&f[12] = *(const float4*)(src + 12);

    const int r16 = b >> 4, ll = b & 15;
    const int kc  = kbase >> 5;
    const int lh0 = (kbase >> 3) & 3;
#pragma unroll
    for (int c = 0; c < 2; ++c) {
        uint4 hi, lo;
        split8(f + 8 * c, hi, lo);
        const size_t dst = ((size_t)(r16 * 128 + kc) * 64 + (lh0 + c) * 16 + ll) * 8;
        *(uint4*)&Ahi[dst] = hi;
        *(uint4*)&Alo[dst] = lo;
    }
}

// ---------------------------------------------------------------------------
// GEMM: grid ceil(V/64) x 256 threads. Wave w owns vocab [v0+16w, +16) x all
// 64 batch rows. B staged per-wave in LDS in 256-float K-windows.
// ---------------------------------------------------------------------------
#define KW   256                  // floats per window per row
#define TPW  8                    // 32-k MFMA tiles per window

__global__ __launch_bounds__(256, 2) void logits_mfma(
    const float* __restrict__ emb,              // [V][H] fp32
    const unsigned short* __restrict__ Ahi,     // frag-ordered bf16
    const unsigned short* __restrict__ Alo,
    const float* __restrict__ temps,            // [B]
    const float* __restrict__ bias,             // [V]
    float*       __restrict__ out,              // [B][V] scaled logits
    int V, int H)
{
    __shared__ float sB[64 * KW];               // 64 KB, per-wave-private strips

    const int tid  = threadIdx.x;
    const int lane = tid & 63;
    const int w    = tid >> 6;
    const int v0   = blockIdx.x * 64;

    const int ll = lane & 15;                   // frag col (vocab) / row idx
    const int lh = lane >> 4;                   // k sub-chunk

    const int NWIN = H / KW;                    // 16
    const int NT   = H >> 5;                    // 128 k-tiles total

    // read-side row + swizzle (row_local = 16w + ll, private to wave w)
    const int rl   = 16 * w + ll;
    const int fswz = ((rl & 7) << 3) ^ (((rl >> 3) & 1) << 2);

    // A fragment base offset (elements); i = batch 16-block 0..3
    const size_t aoff = (size_t)lh * 128 + (size_t)ll * 8;

    float4 pf[16];                  // one window of B, 1 row per register
    bf16x8 aih[2][4], ail[2][4];    // A frags, parity double buffer
    f32x4  acc[4];
#pragma unroll
    for (int i = 0; i < 4; ++i) acc[i] = (f32x4){0.f, 0.f, 0.f, 0.f};

#define LOADW(win) do {                                                       \
    const int wb = (win) * KW;                                                \
    _Pragma("unroll")                                                         \
    for (int i = 0; i < 16; ++i) {                                            \
        int rg = v0 + 16 * w + i;                                             \
        rg = (rg < V) ? rg : (V - 1);                                         \
        pf[i] = *(const float4*)(emb + (size_t)rg * H + wb + lane * 4);       \
    }                                                                         \
} while (0)

#define STOREW() do {                                                         \
    _Pragma("unroll")                                                         \
    for (int i = 0; i < 16; ++i) {                                            \
        const int row = 16 * w + i;                                           \
        const int sz  = ((i & 7) << 3) ^ (((i >> 3) & 1) << 2);               \
        *(float4*)&sB[row * KW + ((lane * 4) ^ sz)] = pf[i];                  \
    }                                                                         \
} while (0)

#define LOADA(t, p) do {                                                      \
    _Pragma("unroll")                                                         \
    for (int i = 0; i < 4; ++i) {                                             \
        const size_t ai = aoff + (size_t)i * 65536 + (size_t)(t) * 512;       \
        aih[p][i] = *(const bf16x8*)&Ahi[ai];                                 \
        ail[p][i] = *(const bf16x8*)&Alo[ai];                                 \
    }                                                                         \
} while (0)

    // prologue: window 0 staged, A tile 0 in parity 0
    LOADW(0);
    STOREW();
    LOADA(0, 0);

    for (int win = 0; win < NWIN; ++win) {
        if (win + 1 < NWIN) LOADW(win + 1);     // 1 KB/row bursts, in flight
#pragma unroll
        for (int kt = 0; kt < TPW; ++kt) {
            const int t = win * TPW + kt;
            const int p = t & 1;
            if (t + 1 < NT) LOADA(t + 1, p ^ 1);

            // B frag from LDS (fp32) -> split
            const int kb = kt * 32 + lh * 8;
            float f[8];
            *(float4*)&f[0] = *(const float4*)&sB[rl * KW + ((kb)     ^ fswz)];
            *(float4*)&f[4] = *(const float4*)&sB[rl * KW + ((kb + 4) ^ fswz)];
            bf16x8 fbh, fbl;
            split8v(f, fbh, fbl);

#pragma unroll
            for (int i = 0; i < 4; ++i) {
                acc[i] = __builtin_amdgcn_mfma_f32_16x16x32_bf16(
                    ail[p][i], fbh, acc[i], 0, 0, 0);
                acc[i] = __builtin_amdgcn_mfma_f32_16x16x32_bf16(
                    aih[p][i], fbl, acc[i], 0, 0, 0);
                acc[i] = __builtin_amdgcn_mfma_f32_16x16x32_bf16(
                    aih[p][i], fbh, acc[i], 0, 0, 0);
            }
        }
        if (win + 1 < NWIN) STOREW();           // waits vmcnt; wave-private LDS
    }
#undef LOADW
#undef STOREW
#undef LOADA

    // epilogue: C col = ll (vocab), row = lh*4 + r within 16-batch block i
    const int vv = v0 + 16 * w + ll;
    if (vv < V) {
        const float bv = bias[vv];
#pragma unroll
        for (int i = 0; i < 4; ++i)
#pragma unroll
            for (int r = 0; r < 4; ++r) {
                const int b = 16 * i + lh * 4 + r;
                out[(size_t)b * V + vv] = (acc[i][r] + bv) / temps[b];
            }
    }
}

// ---------------------------------------------------------------------------
// JAX threefry2x32 gumbel — partitionable path (verified round 2).
// ---------------------------------------------------------------------------
__device__ __forceinline__ uint32_t rotl32(uint32_t x, int d) {
    return (x << d) | (x >> (32 - d));
}

__device__ float jax_gumbel(uint32_t flat) {
    const uint32_t k0 = 0u, k1 = 42u;
    const uint32_t ks[3] = { k0, k1, k0 ^ k1 ^ 0x1BD11BDAu };
    uint32_t x0 = 0u   + ks[0];
    uint32_t x1 = flat + ks[1];
    const int rot[2][4] = { {13, 15, 26, 6}, {17, 29, 16, 24} };
#pragma unroll
    for (int r = 0; r < 5; ++r) {
        const int* rr = rot[r & 1];
#pragma unroll
        for (int j = 0; j < 4; ++j) {
            x0 += x1;
            x1 = rotl32(x1, rr[j]);
            x1 ^= x0;
        }
        x0 += ks[(r + 1) % 3];
        x1 += ks[(r + 2) % 3] + (uint32_t)(r + 1);
    }
    const uint32_t bits = x0 ^ x1;
    const uint32_t fb = (bits >> 9) | 0x3F800000u;
    const float f = __uint_as_float(fb) - 1.0f;
    const float tiny = 1.17549435e-38f;
    float u = __fadd_rn(__fmul_rn(f, 1.0f), tiny);
    u = fmaxf(tiny, u);
    const float l1 = logf(u);
    return -logf(-l1);
}

// ---------------------------------------------------------------------------
// Per-batch sampling: one block per row. (unchanged, verified round 2)
// ---------------------------------------------------------------------------
#define NBINS 4096
#define CAP   2048
#define NKEEP 64

__global__ __launch_bounds__(256) void sample_kernel(
    const float* __restrict__ logits,  // [B][V] scaled
    const float* __restrict__ top_ps,  // [B]
    const int*   __restrict__ top_ks,  // [B]
    int*         __restrict__ out_ids, // [B]
    int V)
{
    const int b = blockIdx.x;
    const int tid = threadIdx.x;
    const float* row = logits + (size_t)b * V;

    __shared__ float swred[4];
    __shared__ int   bins[NBINS];
    __shared__ int   schunk[256];
    __shared__ int   sThrBin, sCnt, sMkeep;
    __shared__ float cval[CAP];
    __shared__ int   cidx[CAP];
    __shared__ float tval[NKEEP];
    __shared__ int   tidxs[NKEEP];

    // ---- pass 1: row max ----
    float m = -INFINITY;
    for (int k = tid; k < V; k += 256) m = fmaxf(m, row[k]);
#pragma unroll
    for (int o = 32; o > 0; o >>= 1) m = fmaxf(m, __shfl_xor(m, o, 64));
    if ((tid & 63) == 0) swred[tid >> 6] = m;
    __syncthreads();
    m = fmaxf(fmaxf(swred[0], swred[1]), fmaxf(swred[2], swred[3]));

    // ---- zero histogram ----
    for (int k = tid; k < NBINS; k += 256) bins[k] = 0;
    if (tid == 0) sCnt = 0;
    __syncthreads();

    // ---- pass 2: sum(exp(x-m)) + histogram of g = m - x ----
    float s = 0.f;
    for (int k = tid; k < V; k += 256) {
        const float x = row[k];
        s += expf(x - m);
        const float g = m - x;
        int bin = (int)(g * 256.0f);
        if (bin >= NBINS) bin = NBINS - 1;
        atomicAdd(&bins[bin], 1);
    }
#pragma unroll
    for (int o = 32; o > 0; o >>= 1) s += __shfl_xor(s, o, 64);
    __syncthreads();
    if ((tid & 63) == 0) swred[tid >> 6] = s;

    int csum = 0;
#pragma unroll
    for (int k = 0; k < NBINS / 256; ++k) csum += bins[tid * (NBINS / 256) + k];
    schunk[tid] = csum;
    __syncthreads();
    s = swred[0] + swred[1] + swred[2] + swred[3];
    if (tid == 0) {
        int cum = 0, chunk = 255;
        for (int c = 0; c < 256; ++c) {
            if (cum + schunk[c] >= NKEEP) { chunk = c; break; }
            cum += schunk[c];
        }
        int t = NBINS - 1;
        const int base = chunk * (NBINS / 256);
        for (int k = base; k < base + NBINS / 256; ++k) {
            cum += bins[k];
            if (cum >= NKEEP) { t = k; break; }
        }
        sThrBin = t;
    }
    __syncthreads();
    const int thrBin = sThrBin;

    // ---- pass 3: compact candidates ----
    for (int k = tid; k < V; k += 256) {
        const float x = row[k];
        const float g = m - x;
        int bin = (int)(g * 256.0f);
        if (bin >= NBINS) bin = NBINS - 1;
        if (bin <= thrBin) {
            const int p = atomicAdd(&sCnt, 1);
            if (p < CAP) { cval[p] = x; cidx[p] = k; }
        }
    }
    __syncthreads();
    const int C = min(sCnt, CAP);

    // ---- pass 4: rank-select top NKEEP ----
    for (int i = tid; i < C; i += 256) {
        const float vi = cval[i];
        const int   ii = cidx[i];
        int rank = 0;
        for (int j = 0; j < C; ++j) {
            const float vj = cval[j];
            const int   ij = cidx[j];
            rank += (vj > vi) || (vj == vi && ij < ii);
        }
        if (rank < NKEEP) { tval[rank] = vi; tidxs[rank] = ii; }
    }
    __syncthreads();

    // ---- pass 5: serial top-p/top-k cut ----
    if (tid == 0) {
        const float pb = top_ps[b];
        const int   kk = top_ks[b];
        const int   nk = min(NKEEP, C);
        float cum = 0.f;
        int mk = 0;
        for (int r = 0; r < nk; ++r) {
            const float pr = expf(tval[r] - m) / s;
            cum += pr;
            const float excl = cum - pr;
            if (excl > pb || r >= kk) break;
            ++mk;
        }
        sMkeep = (mk > 0) ? mk : 1;
    }
    __syncthreads();
    const int mkeep = sMkeep;

    // ---- pass 6: gumbel argmax over kept prefix ----
    if (tid < 64) {
        float sc = -INFINITY;
        int vid = INT_MAX;
        if (tid < mkeep) {
            const int v = tidxs[tid];
            vid = v;
            sc = tval[tid] + jax_gumbel((uint32_t)b * (uint32_t)V + (uint32_t)v);
        }
#pragma unroll
        for (int o = 32; o > 0; o >>= 1) {
            const float os = __shfl_xor(sc, o, 64);
            const int   ov = __shfl_xor(vid, o, 64);
            if (os > sc || (os == sc && ov < vid)) { sc = os; vid = ov; }
        }
        if (tid == 0) out_ids[b] = vid;
    }
}

extern "C" void kernel_launch(void* const* d_in, const int* in_sizes, int n_in,
                              void* d_out, int out_size, void* d_ws, size_t ws_size,
                              hipStream_t stream)
{
    const float* emb   = (const float*)d_in[0];
    const float* hs    = (const float*)d_in[1];
    const int*   pos   = (const int*)d_in[2];
    const float* temps = (const float*)d_in[3];
    const float* tps   = (const float*)d_in[4];
    const int*   tks   = (const int*)d_in[5];
    const float* bias  = (const float*)d_in[6];

    const int B = in_sizes[3];                     // temperatures
    const int V = in_sizes[6];                     // bias
    const int H = (int)((long long)in_sizes[0] / V);
    const int L = (int)((long long)in_sizes[1] / ((long long)B * H));

    float*          logits = (float*)d_ws;                        // B*V fp32
    unsigned short* Ahi    = (unsigned short*)((char*)d_ws + (16u << 20));
    unsigned short* Alo    = Ahi + (size_t)B * H;                 // 512 KB each

    prep_h<<<(B * H) / (16 * 256), 256, 0, stream>>>(hs, pos, Ahi, Alo, H, L);

    const int nblk = (V + 63) / 64;
    logits_mfma<<<nblk, 256, 0, stream>>>(emb, Ahi, Alo, temps, bias,
                                          logits, V, H);

    sample_kernel<<<B, 256, 0, stream>>>(logits, tps, tks, (int*)d_out, V);
}

// Round 7
// 399.820 us; speedup vs baseline: 1.6789x; 1.6789x over previous
//
#include <hip/hip_runtime.h>
#include <stdint.h>
#include <float.h>
#include <limits.h>

// ---------------------------------------------------------------------------
// Sampler: logits = (h @ E^T + bias) / T; softmax; top-p/top-k mask;
// jax.random.categorical(key(42)) == argmax(logp + gumbel) over kept set.
// GEMM via bf16 MFMA, 3-term split (loA*hiB + hiA*loB + hiA*hiB), k-ascending
// (bit-identical FP order to the verified round-3..6 kernels).
// Round 7: burst staging via global_load_lds (no VGPR transit, no spills).
// Wave-private 16-row LDS strip, half-window (128 floats) double buffer,
// ZERO barriers. Source XOR-pre-swizzle + swizzled ds_read (rule #21).
// ---------------------------------------------------------------------------

typedef __bf16 bf16x8 __attribute__((ext_vector_type(8)));
typedef float  f32x4  __attribute__((ext_vector_type(4)));

__device__ __forceinline__ void split8v(const float* f, bf16x8& hi, bf16x8& lo) {
#pragma unroll
    for (int e = 0; e < 8; ++e) {
        const __bf16 h = (__bf16)f[e];
        hi[e] = h;
        lo[e] = (__bf16)(f[e] - (float)h);
    }
}
__device__ __forceinline__ void split8(const float* f, uint4& hi, uint4& lo) {
    bf16x8 vh, vl;
    split8v(f, vh, vl);
    hi = __builtin_bit_cast(uint4, vh);
    lo = __builtin_bit_cast(uint4, vl);
}

// ---------------------------------------------------------------------------
// prep: h[b, pos, :] -> A_hi/A_lo in MFMA fragment order (verified layout):
// idx = ((r16*128 + kc)*64 + lh*16 + ll)*8 + j ; row = r16*16+ll,
// k = kc*32 + lh*8 + j.
// ---------------------------------------------------------------------------
__global__ __launch_bounds__(256) void prep_h(
    const float* __restrict__ hs, const int* __restrict__ pos_p,
    unsigned short* __restrict__ Ahi, unsigned short* __restrict__ Alo,
    int H, int L)
{
    const int pos = pos_p[0];
    const int tid = blockIdx.x * 256 + threadIdx.x;   // B*H/16 threads
    const int b     = tid >> 8;                       // 0..63
    const int kbase = (tid & 255) * 16;               // 0..4080
    const float* src = hs + ((size_t)b * L + pos) * H + kbase;
    float f[16];
    *(float4*)&f[0]  = *(const float4*)(src);
    *(float4*)&f[4]  = *(const float4*)(src + 4);
    *(float4*)&f[8]  = *(const float4*)(src + 8);
    *(float4*)&f[12] = *(const float4*)(src + 12);

    const int r16 = b >> 4, ll = b & 15;
    const int kc  = kbase >> 5;
    const int lh0 = (kbase >> 3) & 3;
#pragma unroll
    for (int c = 0; c < 2; ++c) {
        uint4 hi, lo;
        split8(f + 8 * c, hi, lo);
        const size_t dst = ((size_t)(r16 * 128 + kc) * 64 + (lh0 + c) * 16 + ll) * 8;
        *(uint4*)&Ahi[dst] = hi;
        *(uint4*)&Alo[dst] = lo;
    }
}

// ---------------------------------------------------------------------------
// GEMM: grid ceil(V/64) x 256 threads. Wave w owns vocab [v0+16w, +16) x all
// 64 batch. B staged via global_load_lds in 128-float half-windows,
// wave-private LDS strip, dbuf halves, no barriers.
// ---------------------------------------------------------------------------
__global__ __launch_bounds__(256, 2) void logits_mfma(
    const float* __restrict__ emb,              // [V][H] fp32
    const unsigned short* __restrict__ Ahi,     // frag-ordered bf16
    const unsigned short* __restrict__ Alo,
    const float* __restrict__ temps,            // [B]
    const float* __restrict__ bias,             // [V]
    float*       __restrict__ out,              // [B][V] scaled logits
    int V, int H)
{
    __shared__ float sB[4 * 4096];              // 64 KB: 4 waves x (2 x 2048 fl)

    const int tid  = threadIdx.x;
    const int lane = tid & 63;
    const int w    = tid >> 6;
    const int v0   = blockIdx.x * 64;

    const int ll = lane & 15;                   // frag col (vocab row idx)
    const int lh = lane >> 4;                   // k sub-chunk
    const int lrow = lane >> 5;                 // stage: row within pair
    const int lcol = lane & 31;                 // stage: 16B unit within 512B

    const int NT = H >> 5;                      // 128 k-tiles
    const int NH = H >> 7;                      // 32 half-windows

    float* swave = &sB[w * 4096];

    // A fragment base offset (elements); i = batch 16-block 0..3
    const size_t aoff = (size_t)lh * 128 + (size_t)ll * 8;

    bf16x8 aih[2][4], ail[2][4];                // A frags, parity buffer
    float4 fB[4][2];                            // one half-window of B frags
    f32x4  acc[4];
#pragma unroll
    for (int i = 0; i < 4; ++i) acc[i] = (f32x4){0.f, 0.f, 0.f, 0.f};

    // stage half-window hw into half-buffer hb: 8 instrs, 2 rows x 512B each
#define STAGE(hw, hb) do {                                                    \
    _Pragma("unroll")                                                         \
    for (int i = 0; i < 16; i += 2) {                                         \
        const int ri = i + lrow;                                              \
        int rg = v0 + w * 16 + ri;                                            \
        rg = (rg < V) ? rg : (V - 1);                                         \
        const float* srcp = emb + (size_t)rg * H + (hw) * 128                 \
                          + ((lcol * 4) ^ ((ri & 7) << 2));                   \
        __builtin_amdgcn_global_load_lds(                                     \
            (const __attribute__((address_space(1))) void*)srcp,              \
            (__attribute__((address_space(3))) void*)&swave[(hb) * 2048 + i * 128], \
            16, 0, 0);                                                        \
    }                                                                         \
} while (0)

    // read one half-window's B frags (per-lane row ll): 8 x ds_read_b128
#define DSREAD(hb) do {                                                       \
    _Pragma("unroll")                                                         \
    for (int kt = 0; kt < 4; ++kt) {                                          \
        _Pragma("unroll")                                                     \
        for (int q = 0; q < 2; ++q) {                                         \
            const int fi = (kt * 32 + lh * 8 + q * 4) ^ ((ll & 7) << 2);      \
            fB[kt][q] = *(const float4*)&swave[(hb) * 2048 + ll * 128 + fi];  \
        }                                                                     \
    }                                                                         \
} while (0)

#define LOADA(t, p) do {                                                      \
    _Pragma("unroll")                                                         \
    for (int i = 0; i < 4; ++i) {                                             \
        const size_t ai = aoff + (size_t)i * 65536 + (size_t)(t) * 512;       \
        aih[p][i] = *(const bf16x8*)&Ahi[ai];                                 \
        ail[p][i] = *(const bf16x8*)&Alo[ai];                                 \
    }                                                                         \
} while (0)

    LOADA(0, 0);
    STAGE(0, 0);

    for (int hw = 0; hw < NH; ++hw) {
        const int hb = hw & 1;
        DSREAD(hb);                       // vmcnt drain covers STAGE(hw) only
        if (hw + 1 < NH) STAGE(hw + 1, hb ^ 1);   // latency hidden by compute

#pragma unroll
        for (int kt = 0; kt < 4; ++kt) {
            const int t = hw * 4 + kt;    // global k-tile; parity = kt&1 (hw*4 even)
            if (t + 1 < NT) LOADA(t + 1, (kt + 1) & 1);

            float f[8];
            *(float4*)&f[0] = fB[kt][0];
            *(float4*)&f[4] = fB[kt][1];
            bf16x8 fbh, fbl;
            split8v(f, fbh, fbl);

#pragma unroll
            for (int i = 0; i < 4; ++i) {
                acc[i] = __builtin_amdgcn_mfma_f32_16x16x32_bf16(
                    ail[kt & 1][i], fbh, acc[i], 0, 0, 0);
                acc[i] = __builtin_amdgcn_mfma_f32_16x16x32_bf16(
                    aih[kt & 1][i], fbl, acc[i], 0, 0, 0);
                acc[i] = __builtin_amdgcn_mfma_f32_16x16x32_bf16(
                    aih[kt & 1][i], fbh, acc[i], 0, 0, 0);
            }
        }
    }
#undef STAGE
#undef DSREAD
#undef LOADA

    // epilogue: C col = ll (vocab), row = lh*4 + r within 16-batch block i
    const int vv = v0 + 16 * w + ll;
    if (vv < V) {
        const float bv = bias[vv];
#pragma unroll
        for (int i = 0; i < 4; ++i)
#pragma unroll
            for (int r = 0; r < 4; ++r) {
                const int b = 16 * i + lh * 4 + r;
                out[(size_t)b * V + vv] = (acc[i][r] + bv) / temps[b];
            }
    }
}

// ---------------------------------------------------------------------------
// JAX threefry2x32 gumbel — partitionable path (verified round 2).
// ---------------------------------------------------------------------------
__device__ __forceinline__ uint32_t rotl32(uint32_t x, int d) {
    return (x << d) | (x >> (32 - d));
}

__device__ float jax_gumbel(uint32_t flat) {
    const uint32_t k0 = 0u, k1 = 42u;
    const uint32_t ks[3] = { k0, k1, k0 ^ k1 ^ 0x1BD11BDAu };
    uint32_t x0 = 0u   + ks[0];
    uint32_t x1 = flat + ks[1];
    const int rot[2][4] = { {13, 15, 26, 6}, {17, 29, 16, 24} };
#pragma unroll
    for (int r = 0; r < 5; ++r) {
        const int* rr = rot[r & 1];
#pragma unroll
        for (int j = 0; j < 4; ++j) {
            x0 += x1;
            x1 = rotl32(x1, rr[j]);
            x1 ^= x0;
        }
        x0 += ks[(r + 1) % 3];
        x1 += ks[(r + 2) % 3] + (uint32_t)(r + 1);
    }
    const uint32_t bits = x0 ^ x1;
    const uint32_t fb = (bits >> 9) | 0x3F800000u;
    const float f = __uint_as_float(fb) - 1.0f;
    const float tiny = 1.17549435e-38f;
    float u = __fadd_rn(__fmul_rn(f, 1.0f), tiny);
    u = fmaxf(tiny, u);
    const float l1 = logf(u);
    return -logf(-l1);
}

// ---------------------------------------------------------------------------
// Per-batch sampling: one block per row. (unchanged, verified round 2)
// ---------------------------------------------------------------------------
#define NBINS 4096
#define CAP   2048
#define NKEEP 64

__global__ __launch_bounds__(256) void sample_kernel(
    const float* __restrict__ logits,  // [B][V] scaled
    const float* __restrict__ top_ps,  // [B]
    const int*   __restrict__ top_ks,  // [B]
    int*         __restrict__ out_ids, // [B]
    int V)
{
    const int b = blockIdx.x;
    const int tid = threadIdx.x;
    const float* row = logits + (size_t)b * V;

    __shared__ float swred[4];
    __shared__ int   bins[NBINS];
    __shared__ int   schunk[256];
    __shared__ int   sThrBin, sCnt, sMkeep;
    __shared__ float cval[CAP];
    __shared__ int   cidx[CAP];
    __shared__ float tval[NKEEP];
    __shared__ int   tidxs[NKEEP];

    // ---- pass 1: row max ----
    float m = -INFINITY;
    for (int k = tid; k < V; k += 256) m = fmaxf(m, row[k]);
#pragma unroll
    for (int o = 32; o > 0; o >>= 1) m = fmaxf(m, __shfl_xor(m, o, 64));
    if ((tid & 63) == 0) swred[tid >> 6] = m;
    __syncthreads();
    m = fmaxf(fmaxf(swred[0], swred[1]), fmaxf(swred[2], swred[3]));

    // ---- zero histogram ----
    for (int k = tid; k < NBINS; k += 256) bins[k] = 0;
    if (tid == 0) sCnt = 0;
    __syncthreads();

    // ---- pass 2: sum(exp(x-m)) + histogram of g = m - x ----
    float s = 0.f;
    for (int k = tid; k < V; k += 256) {
        const float x = row[k];
        s += expf(x - m);
        const float g = m - x;
        int bin = (int)(g * 256.0f);
        if (bin >= NBINS) bin = NBINS - 1;
        atomicAdd(&bins[bin], 1);
    }
#pragma unroll
    for (int o = 32; o > 0; o >>= 1) s += __shfl_xor(s, o, 64);
    __syncthreads();
    if ((tid & 63) == 0) swred[tid >> 6] = s;

    int csum = 0;
#pragma unroll
    for (int k = 0; k < NBINS / 256; ++k) csum += bins[tid * (NBINS / 256) + k];
    schunk[tid] = csum;
    __syncthreads();
    s = swred[0] + swred[1] + swred[2] + swred[3];
    if (tid == 0) {
        int cum = 0, chunk = 255;
        for (int c = 0; c < 256; ++c) {
            if (cum + schunk[c] >= NKEEP) { chunk = c; break; }
            cum += schunk[c];
        }
        int t = NBINS - 1;
        const int base = chunk * (NBINS / 256);
        for (int k = base; k < base + NBINS / 256; ++k) {
            cum += bins[k];
            if (cum >= NKEEP) { t = k; break; }
        }
        sThrBin = t;
    }
    __syncthreads();
    const int thrBin = sThrBin;

    // ---- pass 3: compact candidates ----
    for (int k = tid; k < V; k += 256) {
        const float x = row[k];
        const float g = m - x;
        int bin = (int)(g * 256.0f);
        if (bin >= NBINS) bin = NBINS - 1;
        if (bin <= thrBin) {
            const int p = atomicAdd(&sCnt, 1);
            if (p < CAP) { cval[p] = x; cidx[p] = k; }
        }
    }
    __syncthreads();
    const int C = min(sCnt, CAP);

    // ---- pass 4: rank-select top NKEEP ----
    for (int i = tid; i < C; i += 256) {
        const float vi = cval[i];
        const int   ii = cidx[i];
        int rank = 0;
        for (int j = 0; j < C; ++j) {
            const float vj = cval[j];
            const int   ij = cidx[j];
            rank += (vj > vi) || (vj == vi && ij < ii);
        }
        if (rank < NKEEP) { tval[rank] = vi; tidxs[rank] = ii; }
    }
    __syncthreads();

    // ---- pass 5: serial top-p/top-k cut ----
    if (tid == 0) {
        const float pb = top_ps[b];
        const int   kk = top_ks[b];
        const int   nk = min(NKEEP, C);
        float cum = 0.f;
        int mk = 0;
        for (int r = 0; r < nk; ++r) {
            const float pr = expf(tval[r] - m) / s;
            cum += pr;
            const float excl = cum - pr;
            if (excl > pb || r >= kk) break;
            ++mk;
        }
        sMkeep = (mk > 0) ? mk : 1;
    }
    __syncthreads();
    const int mkeep = sMkeep;

    // ---- pass 6: gumbel argmax over kept prefix ----
    if (tid < 64) {
        float sc = -INFINITY;
        int vid = INT_MAX;
        if (tid < mkeep) {
            const int v = tidxs[tid];
            vid = v;
            sc = tval[tid] + jax_gumbel((uint32_t)b * (uint32_t)V + (uint32_t)v);
        }
#pragma unroll
        for (int o = 32; o > 0; o >>= 1) {
            const float os = __shfl_xor(sc, o, 64);
            const int   ov = __shfl_xor(vid, o, 64);
            if (os > sc || (os == sc && ov < vid)) { sc = os; vid = ov; }
        }
        if (tid == 0) out_ids[b] = vid;
    }
}

extern "C" void kernel_launch(void* const* d_in, const int* in_sizes, int n_in,
                              void* d_out, int out_size, void* d_ws, size_t ws_size,
                              hipStream_t stream)
{
    const float* emb   = (const float*)d_in[0];
    const float* hs    = (const float*)d_in[1];
    const int*   pos   = (const int*)d_in[2];
    const float* temps = (const float*)d_in[3];
    const float* tps   = (const float*)d_in[4];
    const int*   tks   = (const int*)d_in[5];
    const float* bias  = (const float*)d_in[6];

    const int B = in_sizes[3];                     // temperatures
    const int V = in_sizes[6];                     // bias
    const int H = (int)((long long)in_sizes[0] / V);
    const int L = (int)((long long)in_sizes[1] / ((long long)B * H));

    float*          logits = (float*)d_ws;                        // B*V fp32
    unsigned short* Ahi    = (unsigned short*)((char*)d_ws + (16u << 20));
    unsigned short* Alo    = Ahi + (size_t)B * H;                 // 512 KB each

    prep_h<<<(B * H) / (16 * 256), 256, 0, stream>>>(hs, pos, Ahi, Alo, H, L);

    const int nblk = (V + 63) / 64;
    logits_mfma<<<nblk, 256, 0, stream>>>(emb, Ahi, Alo, temps, bias,
                                          logits, V, H);

    sample_kernel<<<B, 256, 0, stream>>>(logits, tps, tks, (int*)d_out, V);
}

// Round 8
// 381.707 us; speedup vs baseline: 1.7586x; 1.0475x over previous
//
#include <hip/hip_runtime.h>
#include <stdint.h>
#include <float.h>
#include <limits.h>

// ---------------------------------------------------------------------------
// Sampler: logits = (h @ E^T + bias) / T; softmax; top-p/top-k mask;
// jax.random.categorical(key(42)) == argmax(logp + gumbel) over kept set.
// GEMM via bf16 MFMA, 3-term split (loA*hiB + hiA*loB + hiA*hiB).
// Round 8: DRAM-locality restructure. Vocab-tile 16 (contiguous 256 KB/block),
// K-window 512 floats staged as 2 KB/row sequential bursts via global_load_lds,
// per-block k-phase rotation (window start = (blockIdx&3)*2, wraps mod 8),
// 2-barrier double-buffered window loop. Wave = 16 batch x 16 vocab.
// ---------------------------------------------------------------------------

typedef __bf16 bf16x8 __attribute__((ext_vector_type(8)));
typedef float  f32x4  __attribute__((ext_vector_type(4)));

__device__ __forceinline__ void split8v(const float* f, bf16x8& hi, bf16x8& lo) {
#pragma unroll
    for (int e = 0; e < 8; ++e) {
        const __bf16 h = (__bf16)f[e];
        hi[e] = h;
        lo[e] = (__bf16)(f[e] - (float)h);
    }
}
__device__ __forceinline__ void split8(const float* f, uint4& hi, uint4& lo) {
    bf16x8 vh, vl;
    split8v(f, vh, vl);
    hi = __builtin_bit_cast(uint4, vh);
    lo = __builtin_bit_cast(uint4, vl);
}

// ---------------------------------------------------------------------------
// prep: h[b, pos, :] -> A_hi/A_lo in MFMA fragment order (verified layout):
// idx = ((r16*(H/32) + kc)*64 + lh*16 + ll)*8 + j ; row = r16*16+ll,
// k = kc*32 + lh*8 + j.
// ---------------------------------------------------------------------------
__global__ __launch_bounds__(256) void prep_h(
    const float* __restrict__ hs, const int* __restrict__ pos_p,
    unsigned short* __restrict__ Ahi, unsigned short* __restrict__ Alo,
    int H, int L)
{
    const int pos = pos_p[0];
    const int tid = blockIdx.x * 256 + threadIdx.x;   // B*H/16 threads
    const int b     = tid >> 8;                       // 0..63
    const int kbase = (tid & 255) * 16;               // 0..4080
    const float* src = hs + ((size_t)b * L + pos) * H + kbase;
    float f[16];
    *(float4*)&f[0]  = *(const float4*)(src);
    *(float4*)&f[4]  = *(const float4*)(src + 4);
    *(float4*)&f[8]  = *(const float4*)(src + 8);
    *(float4*)&f[12] = *(const float4*)(src + 12);

    const int r16 = b >> 4, ll = b & 15;
    const int kc  = kbase >> 5;
    const int lh0 = (kbase >> 3) & 3;
#pragma unroll
    for (int c = 0; c < 2; ++c) {
        uint4 hi, lo;
        split8(f + 8 * c, hi, lo);
        const size_t dst = ((size_t)(r16 * (H >> 5) + kc) * 64 + (lh0 + c) * 16 + ll) * 8;
        *(uint4*)&Ahi[dst] = hi;
        *(uint4*)&Alo[dst] = lo;
    }
}

// ---------------------------------------------------------------------------
// GEMM: grid ceil(V/16) x 256 thr. Block owns 16 CONTIGUOUS vocab rows;
// wave w computes batch [16w,16w+16) x those 16 rows. B staged in 512-float
// K-windows (2 KB/row bursts), double-buffered, rotated start per block.
// ---------------------------------------------------------------------------
#define NWF    512               // floats per window per row
#define WTILES 16                // 32-k MFMA tiles per window

__global__ __launch_bounds__(256, 2) void logits_mfma(
    const float* __restrict__ emb,              // [V][H] fp32
    const unsigned short* __restrict__ Ahi,     // frag-ordered bf16
    const unsigned short* __restrict__ Alo,
    const float* __restrict__ temps,            // [B]
    const float* __restrict__ bias,             // [V]
    float*       __restrict__ out,              // [B][V] scaled logits
    int V, int H)
{
    __shared__ float sB[2][16 * NWF];           // 2 x 32 KB

    const int tid  = threadIdx.x;
    const int lane = tid & 63;
    const int w    = tid >> 6;
    const int v0   = blockIdx.x * 16;

    const int ll = lane & 15;                   // frag col (vocab row idx)
    const int lh = lane >> 4;                   // k sub-chunk

    const int NWIN = H / NWF;                   // 8 (power of 2)
    const int NTT  = H >> 5;                    // 128 k-tiles
    const int wst  = (blockIdx.x & 3) * 2;      // rotation start window

    // A fragment base: r16-block = w (wave's batch 16-block)
    const size_t aoff = (size_t)w * ((size_t)H * 16)
                      + (size_t)lh * 128 + (size_t)ll * 8;

    bf16x8 aih[2], ail[2];                      // A frags, parity buffer
    f32x4  acc = (f32x4){0.f, 0.f, 0.f, 0.f};

    // stage window win into buffer bf: wave stages rows 4w..4w+3,
    // 2 KB sequential per row (2 x 1KB gload_lds back-to-back).
    // Source pre-XOR-swizzled (within 256B blocks) so linear LDS dest +
    // swizzled read are consistent (rule #21).
#define STAGE(win, bf) do {                                                   \
    _Pragma("unroll")                                                         \
    for (int rr = 0; rr < 4; ++rr) {                                          \
        const int r = w * 4 + rr;                                             \
        int rg = v0 + r;                                                      \
        rg = (rg < V) ? rg : (V - 1);                                         \
        const float* rowp = emb + (size_t)rg * H + (size_t)(win) * NWF        \
                          + ((lane * 4) ^ ((r & 15) << 2));                   \
        _Pragma("unroll")                                                     \
        for (int c = 0; c < 2; ++c) {                                         \
            __builtin_amdgcn_global_load_lds(                                 \
                (const __attribute__((address_space(1))) void*)(rowp + c * 256), \
                (__attribute__((address_space(3))) void*)&sB[bf][r * NWF + c * 256], \
                16, 0, 0);                                                    \
        }                                                                     \
    }                                                                         \
} while (0)

#define LOADA(T, p) do {                                                      \
    const size_t ai = aoff + (size_t)(T) * 512;                               \
    aih[p] = *(const bf16x8*)&Ahi[ai];                                        \
    ail[p] = *(const bf16x8*)&Alo[ai];                                        \
} while (0)

    // prologue
    LOADA(wst * WTILES, 0);
    STAGE(wst, 0);
    __syncthreads();

    for (int ws = 0; ws < NWIN; ++ws) {
        const int bf = ws & 1;
        if (ws + 1 < NWIN) STAGE((wst + ws + 1) & (NWIN - 1), bf ^ 1);

#pragma unroll
        for (int kt = 0; kt < WTILES; ++kt) {
            const int p = kt & 1;
            // prefetch next tile's A frag (L2-hot)
            if (!(ws == NWIN - 1 && kt == WTILES - 1)) {
                const int wsn = ws + ((kt + 1) >> 4);
                const int ktn = (kt + 1) & 15;
                const int T1  = (((wst + wsn) & (NWIN - 1)) << 4) + ktn;
                LOADA(T1, p ^ 1);
            }

            // B frag from LDS (fp32, swizzled) -> split
            const int f0   = kt * 32 + lh * 8;
            const int sidx = ll << 2;
            float f[8];
            *(float4*)&f[0] = *(const float4*)&sB[bf][ll * NWF + ((f0)     ^ sidx)];
            *(float4*)&f[4] = *(const float4*)&sB[bf][ll * NWF + ((f0 + 4) ^ sidx)];
            bf16x8 fbh, fbl;
            split8v(f, fbh, fbl);

            acc = __builtin_amdgcn_mfma_f32_16x16x32_bf16(ail[p], fbh, acc, 0, 0, 0);
            acc = __builtin_amdgcn_mfma_f32_16x16x32_bf16(aih[p], fbl, acc, 0, 0, 0);
            acc = __builtin_amdgcn_mfma_f32_16x16x32_bf16(aih[p], fbh, acc, 0, 0, 0);
        }
        __syncthreads();
    }
#undef STAGE
#undef LOADA

    // epilogue: C col = ll (vocab), row = lh*4 + r (batch within wave block)
    const int vv = v0 + ll;
    if (vv < V) {
        const float bv = bias[vv];
#pragma unroll
        for (int r = 0; r < 4; ++r) {
            const int b = w * 16 + lh * 4 + r;
            out[(size_t)b * V + vv] = (acc[r] + bv) / temps[b];
        }
    }
}

// ---------------------------------------------------------------------------
// JAX threefry2x32 gumbel — partitionable path (verified round 2).
// ---------------------------------------------------------------------------
__device__ __forceinline__ uint32_t rotl32(uint32_t x, int d) {
    return (x << d) | (x >> (32 - d));
}

__device__ float jax_gumbel(uint32_t flat) {
    const uint32_t k0 = 0u, k1 = 42u;
    const uint32_t ks[3] = { k0, k1, k0 ^ k1 ^ 0x1BD11BDAu };
    uint32_t x0 = 0u   + ks[0];
    uint32_t x1 = flat + ks[1];
    const int rot[2][4] = { {13, 15, 26, 6}, {17, 29, 16, 24} };
#pragma unroll
    for (int r = 0; r < 5; ++r) {
        const int* rr = rot[r & 1];
#pragma unroll
        for (int j = 0; j < 4; ++j) {
            x0 += x1;
            x1 = rotl32(x1, rr[j]);
            x1 ^= x0;
        }
        x0 += ks[(r + 1) % 3];
        x1 += ks[(r + 2) % 3] + (uint32_t)(r + 1);
    }
    const uint32_t bits = x0 ^ x1;
    const uint32_t fb = (bits >> 9) | 0x3F800000u;
    const float f = __uint_as_float(fb) - 1.0f;
    const float tiny = 1.17549435e-38f;
    float u = __fadd_rn(__fmul_rn(f, 1.0f), tiny);
    u = fmaxf(tiny, u);
    const float l1 = logf(u);
    return -logf(-l1);
}

// ---------------------------------------------------------------------------
// Per-batch sampling: one block per row. (unchanged, verified round 2)
// ---------------------------------------------------------------------------
#define NBINS 4096
#define CAP   2048
#define NKEEP 64

__global__ __launch_bounds__(256) void sample_kernel(
    const float* __restrict__ logits,  // [B][V] scaled
    const float* __restrict__ top_ps,  // [B]
    const int*   __restrict__ top_ks,  // [B]
    int*         __restrict__ out_ids, // [B]
    int V)
{
    const int b = blockIdx.x;
    const int tid = threadIdx.x;
    const float* row = logits + (size_t)b * V;

    __shared__ float swred[4];
    __shared__ int   bins[NBINS];
    __shared__ int   schunk[256];
    __shared__ int   sThrBin, sCnt, sMkeep;
    __shared__ float cval[CAP];
    __shared__ int   cidx[CAP];
    __shared__ float tval[NKEEP];
    __shared__ int   tidxs[NKEEP];

    // ---- pass 1: row max ----
    float m = -INFINITY;
    for (int k = tid; k < V; k += 256) m = fmaxf(m, row[k]);
#pragma unroll
    for (int o = 32; o > 0; o >>= 1) m = fmaxf(m, __shfl_xor(m, o, 64));
    if ((tid & 63) == 0) swred[tid >> 6] = m;
    __syncthreads();
    m = fmaxf(fmaxf(swred[0], swred[1]), fmaxf(swred[2], swred[3]));

    // ---- zero histogram ----
    for (int k = tid; k < NBINS; k += 256) bins[k] = 0;
    if (tid == 0) sCnt = 0;
    __syncthreads();

    // ---- pass 2: sum(exp(x-m)) + histogram of g = m - x ----
    float s = 0.f;
    for (int k = tid; k < V; k += 256) {
        const float x = row[k];
        s += expf(x - m);
        const float g = m - x;
        int bin = (int)(g * 256.0f);
        if (bin >= NBINS) bin = NBINS - 1;
        atomicAdd(&bins[bin], 1);
    }
#pragma unroll
    for (int o = 32; o > 0; o >>= 1) s += __shfl_xor(s, o, 64);
    __syncthreads();
    if ((tid & 63) == 0) swred[tid >> 6] = s;

    int csum = 0;
#pragma unroll
    for (int k = 0; k < NBINS / 256; ++k) csum += bins[tid * (NBINS / 256) + k];
    schunk[tid] = csum;
    __syncthreads();
    s = swred[0] + swred[1] + swred[2] + swred[3];
    if (tid == 0) {
        int cum = 0, chunk = 255;
        for (int c = 0; c < 256; ++c) {
            if (cum + schunk[c] >= NKEEP) { chunk = c; break; }
            cum += schunk[c];
        }
        int t = NBINS - 1;
        const int base = chunk * (NBINS / 256);
        for (int k = base; k < base + NBINS / 256; ++k) {
            cum += bins[k];
            if (cum >= NKEEP) { t = k; break; }
        }
        sThrBin = t;
    }
    __syncthreads();
    const int thrBin = sThrBin;

    // ---- pass 3: compact candidates ----
    for (int k = tid; k < V; k += 256) {
        const float x = row[k];
        const float g = m - x;
        int bin = (int)(g * 256.0f);
        if (bin >= NBINS) bin = NBINS - 1;
        if (bin <= thrBin) {
            const int p = atomicAdd(&sCnt, 1);
            if (p < CAP) { cval[p] = x; cidx[p] = k; }
        }
    }
    __syncthreads();
    const int C = min(sCnt, CAP);

    // ---- pass 4: rank-select top NKEEP ----
    for (int i = tid; i < C; i += 256) {
        const float vi = cval[i];
        const int   ii = cidx[i];
        int rank = 0;
        for (int j = 0; j < C; ++j) {
            const float vj = cval[j];
            const int   ij = cidx[j];
            rank += (vj > vi) || (vj == vi && ij < ii);
        }
        if (rank < NKEEP) { tval[rank] = vi; tidxs[rank] = ii; }
    }
    __syncthreads();

    // ---- pass 5: serial top-p/top-k cut ----
    if (tid == 0) {
        const float pb = top_ps[b];
        const int   kk = top_ks[b];
        const int   nk = min(NKEEP, C);
        float cum = 0.f;
        int mk = 0;
        for (int r = 0; r < nk; ++r) {
            const float pr = expf(tval[r] - m) / s;
            cum += pr;
            const float excl = cum - pr;
            if (excl > pb || r >= kk) break;
            ++mk;
        }
        sMkeep = (mk > 0) ? mk : 1;
    }
    __syncthreads();
    const int mkeep = sMkeep;

    // ---- pass 6: gumbel argmax over kept prefix ----
    if (tid < 64) {
        float sc = -INFINITY;
        int vid = INT_MAX;
        if (tid < mkeep) {
            const int v = tidxs[tid];
            vid = v;
            sc = tval[tid] + jax_gumbel((uint32_t)b * (uint32_t)V + (uint32_t)v);
        }
#pragma unroll
        for (int o = 32; o > 0; o >>= 1) {
            const float os = __shfl_xor(sc, o, 64);
            const int   ov = __shfl_xor(vid, o, 64);
            if (os > sc || (os == sc && ov < vid)) { sc = os; vid = ov; }
        }
        if (tid == 0) out_ids[b] = vid;
    }
}

extern "C" void kernel_launch(void* const* d_in, const int* in_sizes, int n_in,
                              void* d_out, int out_size, void* d_ws, size_t ws_size,
                              hipStream_t stream)
{
    const float* emb   = (const float*)d_in[0];
    const float* hs    = (const float*)d_in[1];
    const int*   pos   = (const int*)d_in[2];
    const float* temps = (const float*)d_in[3];
    const float* tps   = (const float*)d_in[4];
    const int*   tks   = (const int*)d_in[5];
    const float* bias  = (const float*)d_in[6];

    const int B = in_sizes[3];                     // temperatures
    const int V = in_sizes[6];                     // bias
    const int H = (int)((long long)in_sizes[0] / V);
    const int L = (int)((long long)in_sizes[1] / ((long long)B * H));

    float*          logits = (float*)d_ws;                        // B*V fp32
    unsigned short* Ahi    = (unsigned short*)((char*)d_ws + (16u << 20));
    unsigned short* Alo    = Ahi + (size_t)B * H;                 // 512 KB each

    prep_h<<<(B * H) / (16 * 256), 256, 0, stream>>>(hs, pos, Ahi, Alo, H, L);

    const int nblk = (V + 15) / 16;
    logits_mfma<<<nblk, 256, 0, stream>>>(emb, Ahi, Alo, temps, bias,
                                          logits, V, H);

    sample_kernel<<<B, 256, 0, stream>>>(logits, tps, tks, (int*)d_out, V);
}